// Round 2
// baseline (99.018 us; speedup 1.0000x reference)
//
#include <hip/hip_runtime.h>

// EmbedAtt: out[b,d] = sum_i sigmoid((x_num[b,i]-mean[i])/(std[i]+eps)) * lin_W[i,d]
//                    + sum_i lin_b[i,d]
//                    + sum_c emb[c, x_cat[b,c], d]
// B=65536, CN=CC=16, D=128, V=65. All float arrays fp32, x_cat int32, out fp32.

constexpr int CN = 16;
constexpr int CC = 16;
constexpr int D  = 128;
constexpr int V  = 65;
constexpr float EPS = 1e-5f;
constexpr int ROWS_PER_BLOCK = 8;   // 32 threads/row (float4 each) * 8 rows = 256 threads

__global__ __launch_bounds__(256) void embed_att_kernel(
    const float* __restrict__ x_num,   // [B, CN]
    const float* __restrict__ means,   // [CN]
    const float* __restrict__ stds,    // [CN]
    const float* __restrict__ lin_W,   // [CN, D]
    const float* __restrict__ lin_b,   // [CN, D]
    const float* __restrict__ emb,     // [CC, V, D]
    const int*  __restrict__ x_cat,    // [B, CC]
    float* __restrict__ out)           // [B, D]
{
    __shared__ float z_s[ROWS_PER_BLOCK][CN];    // sigmoid outputs
    __shared__ int   idx_s[ROWS_PER_BLOCK][CC];  // gather indices
    __shared__ float w_s[CN * D];                // lin_W tile (8 KB)
    __shared__ float bsum_s[D];                  // sum_i lin_b[i,:]

    const int tid  = threadIdx.x;
    const int row0 = blockIdx.x * ROWS_PER_BLOCK;

    // ---- stage lin_W: 2048 floats = 512 x float4, 2 passes of 256 ----
    {
        const float4* w4 = (const float4*)lin_W;
        ((float4*)w_s)[tid]       = w4[tid];
        ((float4*)w_s)[tid + 256] = w4[tid + 256];
    }

    // ---- bias column sums (128 threads) ----
    if (tid < D) {
        float s = 0.f;
#pragma unroll
        for (int i = 0; i < CN; ++i) s += lin_b[i * D + tid];
        bsum_s[tid] = s;
    }

    // ---- per-row scalars: 128 threads, thread t -> row t/16, attr t%16 ----
    // (row0+r)*CN + a == row0*CN + t  -> fully coalesced
    if (tid < ROWS_PER_BLOCK * CN) {
        const int r = tid >> 4, a = tid & 15;
        const float x = x_num[row0 * CN + tid];
        const float m = means[a];
        const float s = stds[a];
        const float t = (x - m) / (s + EPS);
        // sigmoid(t) = 1 / (1 + 2^(-t*log2(e)))
        const float e = __builtin_amdgcn_exp2f(t * -1.44269504088896340736f);
        z_s[r][a]   = 1.0f / (1.0f + e);
        idx_s[r][a] = x_cat[row0 * CC + tid];
    }
    __syncthreads();

    const int r   = tid >> 5;   // row within tile
    const int g   = tid & 31;   // d-group of 4 floats
    const int row = row0 + r;

    float acc[4];
    {
        const float4 b = ((const float4*)bsum_s)[g];
        acc[0] = b.x; acc[1] = b.y; acc[2] = b.z; acc[3] = b.w;
    }

    // ---- numeric part: acc += z[r][i] * lin_W[i, g*4..g*4+3] ----
#pragma unroll
    for (int i = 0; i < CN; ++i) {
        const float zi = z_s[r][i];                        // LDS broadcast
        const float4 w = ((const float4*)w_s)[i * 32 + g]; // ds_read_b128
        acc[0] += zi * w.x; acc[1] += zi * w.y;
        acc[2] += zi * w.z; acc[3] += zi * w.w;
    }

    // ---- categorical part: acc += emb[c, idx, g*4..g*4+3] (L2-hit gathers) ----
#pragma unroll
    for (int c = 0; c < CC; ++c) {
        const int idx = idx_s[r][c];
        const float4 e = *(const float4*)&emb[(c * V + idx) * D + g * 4];
        acc[0] += e.x; acc[1] += e.y; acc[2] += e.z; acc[3] += e.w;
    }

    // ---- store float4 (wave writes 2 adjacent rows' 512B chunks) ----
    float4 o; o.x = acc[0]; o.y = acc[1]; o.z = acc[2]; o.w = acc[3];
    *(float4*)&out[row * D + g * 4] = o;
}

extern "C" void kernel_launch(void* const* d_in, const int* in_sizes, int n_in,
                              void* d_out, int out_size, void* d_ws, size_t ws_size,
                              hipStream_t stream) {
    const float* x_num = (const float*)d_in[0];
    const float* means = (const float*)d_in[1];
    const float* stds  = (const float*)d_in[2];
    const float* lin_W = (const float*)d_in[3];
    const float* lin_b = (const float*)d_in[4];
    const float* emb   = (const float*)d_in[5];
    const int*   x_cat = (const int*)d_in[6];
    float* out = (float*)d_out;

    const int nrows = in_sizes[0] / CN;        // B
    const int grid  = nrows / ROWS_PER_BLOCK;  // B = 65536 -> 8192 blocks

    embed_att_kernel<<<grid, 256, 0, stream>>>(x_num, means, stds, lin_W, lin_b,
                                               emb, x_cat, out);
}